// Round 19
// baseline (107.252 us; speedup 1.0000x reference)
//
#include <hip/hip_runtime.h>
#include <hip/hip_bf16.h>

// Problem constants (B=2, S=2048, D=512, H=8, hd=64)
constexpr int Bc = 2, Sc = 2048, Dc = 512, Hc = 8, HDc = 64;
constexpr int Mtot = Bc * Sc;    // 4096
constexpr size_t HEADMAT = (size_t)Bc * Hc * Sc * HDc;  // 2M elems
// softmax in log2 domain
constexpr float SC2  = 0.18033688011112042f;   // 0.125 * log2(e)
constexpr float NEG2 = 14426.950408889634f;    // 10000 * log2(e)

typedef __attribute__((ext_vector_type(8)))  short          short8;
typedef __attribute__((ext_vector_type(8)))  unsigned short ushort8;
typedef __attribute__((ext_vector_type(4)))  float          f32x4;
typedef __attribute__((ext_vector_type(16))) float          f32x16;

#define MFMA16 __builtin_amdgcn_mfma_f32_16x16x32_bf16
#define MFMA32 __builtin_amdgcn_mfma_f32_32x32x16_bf16

static __device__ __forceinline__ unsigned short f32_to_bf16_bits(float f) {
    unsigned int u = __builtin_bit_cast(unsigned int, f);
    unsigned int r = u + 0x7FFFu + ((u >> 16) & 1u);   // RNE
    return (unsigned short)(r >> 16);
}
static __device__ __forceinline__ unsigned int pk2bf(float a, float b) {
    union { __hip_bfloat162 h2; unsigned int u; } cv;
    cv.h2 = __float22bfloat162_rn(make_float2(a, b));   // HW v_cvt_pk path
    return cv.u;
}

// ---------------------------------------------------------------------------
// x f32 -> bf16
// ---------------------------------------------------------------------------
__global__ __launch_bounds__(256)
void convert_x(const float* __restrict__ x, unsigned short* __restrict__ Xb, int n)
{
    const int i = (blockIdx.x * 256 + threadIdx.x) * 4;
    if (i >= n) return;
    const float4 v = *(const float4*)(x + i);
    ushort4 o;
    o.x = f32_to_bf16_bits(v.x);
    o.y = f32_to_bf16_bits(v.y);
    o.z = f32_to_bf16_bits(v.z);
    o.w = f32_to_bf16_bits(v.w);
    *(ushort4*)(Xb + i) = o;
}

// ---------------------------------------------------------------------------
// W -> W^T bf16
// ---------------------------------------------------------------------------
__global__ __launch_bounds__(256)
void transpose_w(const float* __restrict__ W0, const float* __restrict__ W1,
                 const float* __restrict__ W2, const float* __restrict__ W3,
                 unsigned short* __restrict__ Wt)
{
    __shared__ float T[64][65];
    const int z = blockIdx.z;
    const float* Wp = (z == 0) ? W0 : (z == 1) ? W1 : (z == 2) ? W2 : W3;
    unsigned short* Op = Wt + (size_t)z * 512 * 512;

    const int kt = blockIdx.y * 64, nt = blockIdx.x * 64;
    const int t = threadIdx.x;
    const int r  = t >> 2, c4 = (t & 3) * 16;

    #pragma unroll
    for (int i = 0; i < 4; ++i) {
        const float4 v = *(const float4*)(Wp + (size_t)(kt + r) * 512 + nt + c4 + 4 * i);
        T[r][c4 + 4*i + 0] = v.x;
        T[r][c4 + 4*i + 1] = v.y;
        T[r][c4 + 4*i + 2] = v.z;
        T[r][c4 + 4*i + 3] = v.w;
    }
    __syncthreads();

    const int n = t >> 2, k4 = (t & 3) * 16;
    #pragma unroll
    for (int i = 0; i < 4; ++i) {
        ushort4 o;
        o.x = f32_to_bf16_bits(T[k4 + 4*i + 0][n]);
        o.y = f32_to_bf16_bits(T[k4 + 4*i + 1][n]);
        o.z = f32_to_bf16_bits(T[k4 + 4*i + 2][n]);
        o.w = f32_to_bf16_bits(T[k4 + 4*i + 3][n]);
        *(ushort4*)(Op + (size_t)(nt + n) * 512 + kt + k4 + 4 * i) = o;
    }
}

// ---------------------------------------------------------------------------
// Tiled bf16 MFMA GEMM. HEADOUT: Q (z=0, PRE-SCALED by SC2) and K (z=1)
// head-major [z][B][H][S][64]; V (z=2) BLOCKED [B][H][s/32][64][s%32].
// else: f32 row-major [M][512]. (Verified R9-R18.)
// ---------------------------------------------------------------------------
template<bool HEADOUT>
__global__ __launch_bounds__(256)
void gemm_tile(const unsigned short* __restrict__ Xb,
               const unsigned short* __restrict__ Wt,
               const float* __restrict__ b0, const float* __restrict__ b1,
               const float* __restrict__ b2,
               unsigned short* __restrict__ Hout,
               float* __restrict__ Yf)
{
    __shared__ short As[128 * 32];
    __shared__ short Bs[64 * 32];

    const int lane = threadIdx.x & 63, wave = threadIdx.x >> 6;
    const int c = lane & 15, g = lane >> 4;
    const int wr = wave >> 1, wc = wave & 1;
    const int z = blockIdx.z;
    const unsigned short* Wp = Wt + (size_t)z * 512 * 512;
    const float* bp = (z == 0) ? b0 : (z == 1) ? b1 : b2;
    const int bm = blockIdx.y * 128;
    const int bn = blockIdx.x * 64;

    const int srow = lane >> 2;
    const int scol = (lane & 3) * 8;

    f32x4 acc[4][2] = {};

    for (int k0 = 0; k0 < 512; k0 += 32) {
        __syncthreads();
        #pragma unroll
        for (int i = 0; i < 2; ++i) {
            const int row = (wave * 2 + i) * 16 + srow;
            const short8 v = *(const short8*)(Xb + (size_t)(bm + row) * 512 + k0 + scol);
            *(short8*)(&As[row * 32 + scol]) = v;
        }
        {
            const int row = wave * 16 + srow;
            const short8 v = *(const short8*)(Wp + (size_t)(bn + row) * 512 + k0 + scol);
            *(short8*)(&Bs[row * 32 + scol]) = v;
        }
        __syncthreads();

        short8 a[4], bfr[2];
        #pragma unroll
        for (int mi = 0; mi < 4; ++mi)
            a[mi] = *(const short8*)(&As[(wr * 64 + mi * 16 + c) * 32 + g * 8]);
        #pragma unroll
        for (int ni = 0; ni < 2; ++ni)
            bfr[ni] = *(const short8*)(&Bs[(wc * 32 + ni * 16 + c) * 32 + g * 8]);
        #pragma unroll
        for (int mi = 0; mi < 4; ++mi)
            #pragma unroll
            for (int ni = 0; ni < 2; ++ni)
                acc[mi][ni] = MFMA16(a[mi], bfr[ni], acc[mi][ni], 0, 0, 0);
    }

    #pragma unroll
    for (int mi = 0; mi < 4; ++mi) {
        #pragma unroll
        for (int ni = 0; ni < 2; ++ni) {
            const int n = bn + wc * 32 + ni * 16 + c;
            const float bias = bp[n];
            float v[4];
            #pragma unroll
            for (int r = 0; r < 4; ++r) {
                v[r] = fmaxf(acc[mi][ni][r] + bias, 0.0f);
                if (HEADOUT && z == 0) v[r] *= SC2;   // pre-scale Q
            }
            const int mbase = bm + wr * 64 + mi * 16 + 4 * g;
            if constexpr (HEADOUT) {
                const int bb = mbase >> 11, ss = mbase & 2047;
                const int hh = n >> 6, hd = n & 63;
                if (z == 2) {
                    // V blocked: panel = ss>>5, elem = hd*32 + (ss&31)
                    union { ushort4 u; unsigned short s[4]; } pk;
                    #pragma unroll
                    for (int r = 0; r < 4; ++r) pk.s[r] = f32_to_bf16_bits(v[r]);
                    *reinterpret_cast<ushort4*>(
                        Hout + (size_t)2 * HEADMAT +
                        (size_t)(bb * Hc + hh) * Sc * HDc +
                        (size_t)(ss >> 5) * (HDc * 32) + hd * 32 + (ss & 31)) = pk.u;
                } else {
                    #pragma unroll
                    for (int r = 0; r < 4; ++r)
                        Hout[(size_t)z * HEADMAT +
                             (((size_t)(bb * Hc + hh) * Sc + ss + r) * HDc + hd)] =
                            f32_to_bf16_bits(v[r]);
                }
            } else {
                #pragma unroll
                for (int r = 0; r < 4; ++r)
                    Yf[(size_t)(mbase + r) * 512 + n] = v[r];
            }
        }
    }
}

// ---------------------------------------------------------------------------
// Split-K flash attention, v15 = R18 + KVBLK=64 + defer-rescale (T13).
// 64 keys/iteration: two independent QK chains (s0,s1), ONE softmax
// bookkeeping pass (tmax shfl / __any / rescale / loop overhead) per 64 keys.
// Defer-rescale: only rescale when __any(tmax > m + 8) (log2 domain;
// p bounded by 2^8, f32/bf16-safe -- T13-verified recipe).
// Tail subtiles beyond kend are exact: causal -NEG2 underflows p to 0.0f,
// and all reads stay in-bounds (kend+63 < Sc whenever a tail exists).
// ---------------------------------------------------------------------------
__global__ __launch_bounds__(256)
void attn_mfma(const short* __restrict__ Qh, const short* __restrict__ Kh,
               const short* __restrict__ Vb, const int* __restrict__ mask,
               unsigned short* __restrict__ Ob)
{
    // per-wave overlay: Lacc[64][33] f32 (8448B); Lml 256B/wave
    __shared__ __align__(16) char smem[4 * 8448 + 4 * 256];

    const int lane = threadIdx.x & 63;
    const int wave = threadIdx.x >> 6;
    const int bid  = blockIdx.x;                    // 1024 blocks
    const int swz  = (bid & 7) * 128 + (bid >> 3);  // XCD-chunked, bijective
    const int t    = 63 - (swz & 63);               // LPT: big tiles first
    const int h    = (swz >> 6) & 7;
    const int b    = swz >> 9;
    const int q0   = t * 32;
    const int r32  = lane & 31;
    const int hi   = lane >> 5;

    char*  wreg = smem + wave * 8448;
    float* Lml  = (float*)(smem + 4 * 8448 + wave * 256);

    const size_t headoff = (size_t)(b * Hc + h) * Sc * HDc;
    const short* Qp = Qh + headoff;
    const short* Kp = Kh + headoff;
    const short* Vp = Vb + headoff;                 // blocked [S/32][64][32]
    const int* mb = mask + b * Sc;

    // first unmasked key (block-uniform)
    int fb = Sc;
    for (int base = 0; base < Sc; base += 64) {
        unsigned long long bal = __ballot(mb[base + lane] != 0);
        if (bal) { fb = base + (__ffsll(bal) - 1); break; }
    }
    const int kmax = (fb <= q0) ? (q0 + 32) : Sc;
    const int kend = (kmax + 31) & ~31;
    const int nT64 = (kend + 63) >> 6;              // 64-key tiles
    const int tpw  = (nT64 + 3) >> 2;
    const int kbeg = wave * tpw * 64;
    const int kfin = min(nT64 * 64, kbeg + tpw * 64);

    // Q fragments (B-operand): Q[q=r32][d = 16j + 8hi + e]  (pre-scaled)
    short8 qf[4];
    #pragma unroll
    for (int j = 0; j < 4; ++j)
        qf[j] = *(const short8*)(Qp + (size_t)(q0 + r32) * HDc + j * 16 + hi * 8);

    f32x16 acc0 = {0,0,0,0,0,0,0,0,0,0,0,0,0,0,0,0};
    f32x16 acc1 = {0,0,0,0,0,0,0,0,0,0,0,0,0,0,0,0};
    float m = -1e30f, l = 0.0f;

    // per-lane V offsets within a panel (elements)
    const int vo0 = r32 * 32 + 8 * hi;
    const int vo1 = (32 + r32) * 32 + 8 * hi;

    for (int k0 = kbeg; k0 < kfin; k0 += 64) {
        // --- V fragments for both 32-key panels
        const short* vpan = Vp + (size_t)k0 * 64;
        const short8 va0 = *(const short8*)(vpan + vo0);
        const short8 va1 = *(const short8*)(vpan + vo0 + 16);
        const short8 vb0 = *(const short8*)(vpan + vo1);
        const short8 vb1 = *(const short8*)(vpan + vo1 + 16);
        const short8 va2 = *(const short8*)(vpan + 2048 + vo0);
        const short8 va3 = *(const short8*)(vpan + 2048 + vo0 + 16);
        const short8 vb2 = *(const short8*)(vpan + 2048 + vo1);
        const short8 vb3 = *(const short8*)(vpan + 2048 + vo1 + 16);

        // --- QK^T: two independent accumulation chains
        f32x16 s0 = {0,0,0,0,0,0,0,0,0,0,0,0,0,0,0,0};
        f32x16 s1 = {0,0,0,0,0,0,0,0,0,0,0,0,0,0,0,0};
        #pragma unroll
        for (int j = 0; j < 4; ++j) {
            const short8 kf0 =
                *(const short8*)(Kp + (size_t)(k0 + r32) * HDc + j * 16 + hi * 8);
            const short8 kf1 =
                *(const short8*)(Kp + (size_t)(k0 + 32 + r32) * HDc + j * 16 + hi * 8);
            s0 = MFMA32(kf0, qf[j], s0, 0, 0, 0);
            s1 = MFMA32(kf1, qf[j], s1, 0, 0, 0);
        }

        // --- padding-mask bits for both subtiles
        const unsigned long long balA = __ballot(mb[k0 + r32] != 0);
        const unsigned long long balB = __ballot(mb[k0 + 32 + r32] != 0);
        const unsigned int mlocA = ((unsigned int)balA) >> (4 * hi);
        const unsigned int mlocB = ((unsigned int)balB) >> (4 * hi);

        float eA[16], eB[16];
        float tmax = -1e30f;
        if (k0 + 63 > q0) {   // diagonal region: causal compares needed
            #pragma unroll
            for (int r = 0; r < 16; ++r) {
                const int cr0 = (r & 3) + 8 * (r >> 2);
                float e0 = s0[r];
                float e1 = s1[r];
                if (!((mlocA >> cr0) & 1))                 e0 -= NEG2;
                if (!((mlocB >> cr0) & 1))                 e1 -= NEG2;
                if (k0 + cr0 + 4 * hi > q0 + r32)          e0 -= NEG2;
                if (k0 + 32 + cr0 + 4 * hi > q0 + r32)     e1 -= NEG2;
                eA[r] = e0; eB[r] = e1;
                tmax = fmaxf(tmax, fmaxf(e0, e1));
            }
        } else {
            #pragma unroll
            for (int r = 0; r < 16; ++r) {
                const int cr0 = (r & 3) + 8 * (r >> 2);
                float e0 = s0[r];
                float e1 = s1[r];
                if (!((mlocA >> cr0) & 1)) e0 -= NEG2;
                if (!((mlocB >> cr0) & 1)) e1 -= NEG2;
                eA[r] = e0; eB[r] = e1;
                tmax = fmaxf(tmax, fmaxf(e0, e1));
            }
        }
        tmax = fmaxf(tmax, __shfl_xor(tmax, 32));   // full-row max

        // --- defer-rescale (T13): tolerate p up to 2^8 before rescaling
        if (__any(tmax > m + 8.0f)) {
            const float mn   = fmaxf(m, tmax);
            const float corr = __builtin_exp2f(m - mn);
            m = mn; l *= corr;
            acc0 *= corr;
            acc1 *= corr;
        }

        float ps = 0.f;
        #pragma unroll
        for (int r = 0; r < 16; ++r) {
            eA[r] = __builtin_exp2f(eA[r] - m);
            eB[r] = __builtin_exp2f(eB[r] - m);
            ps += eA[r] + eB[r];
        }
        l += ps;

        // --- pack P pairs (HW cvt_pk) and exchange across lane-halves
        const unsigned int A0 = pk2bf(eA[0],  eA[1]),  B0 = pk2bf(eA[2],  eA[3]);
        const unsigned int C0 = pk2bf(eA[4],  eA[5]),  D0 = pk2bf(eA[6],  eA[7]);
        const unsigned int A1 = pk2bf(eA[8],  eA[9]),  B1 = pk2bf(eA[10], eA[11]);
        const unsigned int C1 = pk2bf(eA[12], eA[13]), D1 = pk2bf(eA[14], eA[15]);
        const unsigned int A2 = pk2bf(eB[0],  eB[1]),  B2 = pk2bf(eB[2],  eB[3]);
        const unsigned int C2 = pk2bf(eB[4],  eB[5]),  D2 = pk2bf(eB[6],  eB[7]);
        const unsigned int A3 = pk2bf(eB[8],  eB[9]),  B3 = pk2bf(eB[10], eB[11]);
        const unsigned int C3 = pk2bf(eB[12], eB[13]), D3 = pk2bf(eB[14], eB[15]);

        const unsigned int A0s = (unsigned int)__shfl_xor((int)A0, 32);
        const unsigned int B0s = (unsigned int)__shfl_xor((int)B0, 32);
        const unsigned int C0s = (unsigned int)__shfl_xor((int)C0, 32);
        const unsigned int D0s = (unsigned int)__shfl_xor((int)D0, 32);
        const unsigned int A1s = (unsigned int)__shfl_xor((int)A1, 32);
        const unsigned int B1s = (unsigned int)__shfl_xor((int)B1, 32);
        const unsigned int C1s = (unsigned int)__shfl_xor((int)C1, 32);
        const unsigned int D1s = (unsigned int)__shfl_xor((int)D1, 32);
        const unsigned int A2s = (unsigned int)__shfl_xor((int)A2, 32);
        const unsigned int B2s = (unsigned int)__shfl_xor((int)B2, 32);
        const unsigned int C2s = (unsigned int)__shfl_xor((int)C2, 32);
        const unsigned int D2s = (unsigned int)__shfl_xor((int)D2, 32);
        const unsigned int A3s = (unsigned int)__shfl_xor((int)A3, 32);
        const unsigned int B3s = (unsigned int)__shfl_xor((int)B3, 32);
        const unsigned int C3s = (unsigned int)__shfl_xor((int)C3, 32);
        const unsigned int D3s = (unsigned int)__shfl_xor((int)D3, 32);

        union { unsigned int u[4]; short8 s8; } P0, P1, P2, P3;
        P0.u[0] = hi ? C0s : A0;  P0.u[1] = hi ? D0s : B0;
        P0.u[2] = hi ? C0  : A0s; P0.u[3] = hi ? D0  : B0s;
        P1.u[0] = hi ? C1s : A1;  P1.u[1] = hi ? D1s : B1;
        P1.u[2] = hi ? C1  : A1s; P1.u[3] = hi ? D1  : B1s;
        P2.u[0] = hi ? C2s : A2;  P2.u[1] = hi ? D2s : B2;
        P2.u[2] = hi ? C2  : A2s; P2.u[3] = hi ? D2  : B2s;
        P3.u[0] = hi ? C3s : A3;  P3.u[1] = hi ? D3s : B3;
        P3.u[2] = hi ? C3  : A3s; P3.u[3] = hi ? D3  : B3s;

        // --- PV: O^T += V^T_frag x P_frag (two independent chains)
        acc0 = MFMA32(va0, P0.s8, acc0, 0, 0, 0);
        acc1 = MFMA32(vb0, P0.s8, acc1, 0, 0, 0);
        acc0 = MFMA32(va1, P1.s8, acc0, 0, 0, 0);
        acc1 = MFMA32(vb1, P1.s8, acc1, 0, 0, 0);
        acc0 = MFMA32(va2, P2.s8, acc0, 0, 0, 0);
        acc1 = MFMA32(vb2, P2.s8, acc1, 0, 0, 0);
        acc0 = MFMA32(va3, P3.s8, acc0, 0, 0, 0);
        acc1 = MFMA32(vb3, P3.s8, acc1, 0, 0, 0);
    }

    l += __shfl_xor(l, 32);   // full-row denominator for this wave

    // dump partials into OWN overlay region
    {
        float* Lacc = (float*)wreg;   // [64][33]
        #pragma unroll
        for (int r = 0; r < 16; ++r) {
            Lacc[lane * 33 + r]      = acc0[r];
            Lacc[lane * 33 + 16 + r] = acc1[r];
        }
        if (lane < 32) { Lml[lane] = m; Lml[32 + lane] = l; }
    }
    __syncthreads();

    // combine: per-lane weights (q = r32); wave w handles regs [8w, 8w+8)
    float mu[4], lu[4], M = -1e30f;
    #pragma unroll
    for (int u = 0; u < 4; ++u) {
        const float* LmlU = (const float*)(smem + 4 * 8448 + u * 256);
        mu[u] = LmlU[r32];
        lu[u] = LmlU[32 + r32];
        M = fmaxf(M, mu[u]);
    }
    float wgt[4], L = 0.f;
    #pragma unroll
    for (int u = 0; u < 4; ++u) {
        wgt[u] = __builtin_exp2f(mu[u] - M);
        L += wgt[u] * lu[u];
    }
    const float invL = 1.0f / L;

    #pragma unroll
    for (int jj = 0; jj < 8; ++jj) {
        const int j = wave * 8 + jj;
        float o = 0.f;
        #pragma unroll
        for (int u = 0; u < 4; ++u)
            o += wgt[u] * ((const float*)(smem + u * 8448))[lane * 33 + j];
        const int j16 = j & 15;
        const int d = (j16 & 3) + 8 * (j16 >> 2) + 4 * hi + 32 * (j >> 4);
        Ob[(size_t)(b * Sc + q0 + r32) * Dc + h * HDc + d] =
            f32_to_bf16_bits(o * invL);
    }
}

// ---------------------------------------------------------------------------
extern "C" void kernel_launch(void* const* d_in, const int* in_sizes, int n_in,
                              void* d_out, int out_size, void* d_ws, size_t ws_size,
                              hipStream_t stream) {
    const float* x  = (const float*)d_in[0];
    const int* mask = (const int*)d_in[1];
    const float* Wq = (const float*)d_in[2];
    const float* bq = (const float*)d_in[3];
    const float* Wk = (const float*)d_in[4];
    const float* bk = (const float*)d_in[5];
    const float* Wv = (const float*)d_in[6];
    const float* bv = (const float*)d_in[7];
    const float* Wo = (const float*)d_in[8];
    const float* bo = (const float*)d_in[9];
    float* out = (float*)d_out;   // reference output dtype is float32

    unsigned short* Xb = (unsigned short*)d_ws;          // 4 MB
    unsigned short* Wt = Xb + (size_t)Mtot * 512;        // 2 MB
    unsigned short* Qh = Wt + (size_t)4 * 512 * 512;     // head-major (xSC2)
    unsigned short* Kh = Qh + HEADMAT;                   // head-major
    unsigned short* Vb = Kh + HEADMAT;                   // BLOCKED panels
    unsigned short* Ob = Vb + HEADMAT;

    convert_x<<<dim3((Mtot * 512) / 1024), dim3(256), 0, stream>>>(
        x, Xb, Mtot * 512);
    transpose_w<<<dim3(8, 8, 4), dim3(256), 0, stream>>>(Wq, Wk, Wv, Wo, Wt);
    gemm_tile<true><<<dim3(8, Mtot / 128, 3), dim3(256), 0, stream>>>(
        Xb, Wt, bq, bk, bv, Qh, nullptr);
    attn_mfma<<<dim3(1024), dim3(256), 0, stream>>>(
        (const short*)Qh, (const short*)Kh, (const short*)Vb, mask, Ob);
    gemm_tile<false><<<dim3(8, Mtot / 128, 1), dim3(256), 0, stream>>>(
        Ob, Wt + (size_t)3 * 512 * 512, bo, bo, bo, nullptr, out);
}

// Round 20
// 91.681 us; speedup vs baseline: 1.1698x; 1.1698x over previous
//
#include <hip/hip_runtime.h>
#include <hip/hip_bf16.h>

// Problem constants (B=2, S=2048, D=512, H=8, hd=64)
constexpr int Bc = 2, Sc = 2048, Dc = 512, Hc = 8, HDc = 64;
constexpr int Mtot = Bc * Sc;    // 4096
constexpr size_t HEADMAT = (size_t)Bc * Hc * Sc * HDc;  // 2M elems
// softmax in log2 domain
constexpr float SC2  = 0.18033688011112042f;   // 0.125 * log2(e)
constexpr float NEG2 = 14426.950408889634f;    // 10000 * log2(e)

typedef __attribute__((ext_vector_type(8)))  short          short8;
typedef __attribute__((ext_vector_type(8)))  unsigned short ushort8;
typedef __attribute__((ext_vector_type(4)))  float          f32x4;
typedef __attribute__((ext_vector_type(16))) float          f32x16;

#define MFMA16 __builtin_amdgcn_mfma_f32_16x16x32_bf16
#define MFMA32 __builtin_amdgcn_mfma_f32_32x32x16_bf16

static __device__ __forceinline__ unsigned short f32_to_bf16_bits(float f) {
    unsigned int u = __builtin_bit_cast(unsigned int, f);
    unsigned int r = u + 0x7FFFu + ((u >> 16) & 1u);   // RNE
    return (unsigned short)(r >> 16);
}
static __device__ __forceinline__ unsigned int pk2bf(float a, float b) {
    union { __hip_bfloat162 h2; unsigned int u; } cv;
    cv.h2 = __float22bfloat162_rn(make_float2(a, b));   // HW v_cvt_pk path
    return cv.u;
}

// ---------------------------------------------------------------------------
// W -> W^T bf16
// ---------------------------------------------------------------------------
__global__ __launch_bounds__(256)
void transpose_w(const float* __restrict__ W0, const float* __restrict__ W1,
                 const float* __restrict__ W2, const float* __restrict__ W3,
                 unsigned short* __restrict__ Wt)
{
    __shared__ float T[64][65];
    const int z = blockIdx.z;
    const float* Wp = (z == 0) ? W0 : (z == 1) ? W1 : (z == 2) ? W2 : W3;
    unsigned short* Op = Wt + (size_t)z * 512 * 512;

    const int kt = blockIdx.y * 64, nt = blockIdx.x * 64;
    const int t = threadIdx.x;
    const int r  = t >> 2, c4 = (t & 3) * 16;

    #pragma unroll
    for (int i = 0; i < 4; ++i) {
        const float4 v = *(const float4*)(Wp + (size_t)(kt + r) * 512 + nt + c4 + 4 * i);
        T[r][c4 + 4*i + 0] = v.x;
        T[r][c4 + 4*i + 1] = v.y;
        T[r][c4 + 4*i + 2] = v.z;
        T[r][c4 + 4*i + 3] = v.w;
    }
    __syncthreads();

    const int n = t >> 2, k4 = (t & 3) * 16;
    #pragma unroll
    for (int i = 0; i < 4; ++i) {
        ushort4 o;
        o.x = f32_to_bf16_bits(T[k4 + 4*i + 0][n]);
        o.y = f32_to_bf16_bits(T[k4 + 4*i + 1][n]);
        o.z = f32_to_bf16_bits(T[k4 + 4*i + 2][n]);
        o.w = f32_to_bf16_bits(T[k4 + 4*i + 3][n]);
        *(ushort4*)(Op + (size_t)(nt + n) * 512 + kt + k4 + 4 * i) = o;
    }
}

// ---------------------------------------------------------------------------
// Tiled bf16 MFMA GEMM (verified R9-R18 core).
// HEADOUT=true: A = x in FP32 (converted to bf16 during LDS staging --
//   removes the separate convert_x pass); outputs Q (pre-scaled by SC2), K
//   head-major; V BLOCKED [B][H][s/32][64][s%32].
// HEADOUT=false: A = Ob bf16; output f32 row-major [M][512].
// ---------------------------------------------------------------------------
template<bool HEADOUT>
__global__ __launch_bounds__(256)
void gemm_tile(const void* __restrict__ Asrc,
               const unsigned short* __restrict__ Wt,
               const float* __restrict__ b0, const float* __restrict__ b1,
               const float* __restrict__ b2,
               unsigned short* __restrict__ Hout,
               float* __restrict__ Yf)
{
    __shared__ short As[128 * 32];
    __shared__ short Bs[64 * 32];

    const int lane = threadIdx.x & 63, wave = threadIdx.x >> 6;
    const int c = lane & 15, g = lane >> 4;
    const int wr = wave >> 1, wc = wave & 1;
    const int z = blockIdx.z;
    const unsigned short* Wp = Wt + (size_t)z * 512 * 512;
    const float* bp = (z == 0) ? b0 : (z == 1) ? b1 : b2;
    const int bm = blockIdx.y * 128;
    const int bn = blockIdx.x * 64;

    const int srow = lane >> 2;
    const int scol = (lane & 3) * 8;

    f32x4 acc[4][2] = {};

    for (int k0 = 0; k0 < 512; k0 += 32) {
        __syncthreads();
        #pragma unroll
        for (int i = 0; i < 2; ++i) {
            const int row = (wave * 2 + i) * 16 + srow;
            if constexpr (HEADOUT) {
                // f32 source: load 8 floats, convert to bf16 in-flight
                const float* xp = (const float*)Asrc +
                                  (size_t)(bm + row) * 512 + k0 + scol;
                const float4 v0 = *(const float4*)(xp);
                const float4 v1 = *(const float4*)(xp + 4);
                union { unsigned int u[4]; short8 s; } pk;
                pk.u[0] = pk2bf(v0.x, v0.y);
                pk.u[1] = pk2bf(v0.z, v0.w);
                pk.u[2] = pk2bf(v1.x, v1.y);
                pk.u[3] = pk2bf(v1.z, v1.w);
                *(short8*)(&As[row * 32 + scol]) = pk.s;
            } else {
                const short8 v = *(const short8*)((const unsigned short*)Asrc +
                                  (size_t)(bm + row) * 512 + k0 + scol);
                *(short8*)(&As[row * 32 + scol]) = v;
            }
        }
        {
            const int row = wave * 16 + srow;
            const short8 v = *(const short8*)(Wp + (size_t)(bn + row) * 512 + k0 + scol);
            *(short8*)(&Bs[row * 32 + scol]) = v;
        }
        __syncthreads();

        short8 a[4], bfr[2];
        #pragma unroll
        for (int mi = 0; mi < 4; ++mi)
            a[mi] = *(const short8*)(&As[(wr * 64 + mi * 16 + c) * 32 + g * 8]);
        #pragma unroll
        for (int ni = 0; ni < 2; ++ni)
            bfr[ni] = *(const short8*)(&Bs[(wc * 32 + ni * 16 + c) * 32 + g * 8]);
        #pragma unroll
        for (int mi = 0; mi < 4; ++mi)
            #pragma unroll
            for (int ni = 0; ni < 2; ++ni)
                acc[mi][ni] = MFMA16(a[mi], bfr[ni], acc[mi][ni], 0, 0, 0);
    }

    #pragma unroll
    for (int mi = 0; mi < 4; ++mi) {
        #pragma unroll
        for (int ni = 0; ni < 2; ++ni) {
            const int n = bn + wc * 32 + ni * 16 + c;
            const float bias = bp[n];
            float v[4];
            #pragma unroll
            for (int r = 0; r < 4; ++r) {
                v[r] = fmaxf(acc[mi][ni][r] + bias, 0.0f);
                if (HEADOUT && z == 0) v[r] *= SC2;   // pre-scale Q
            }
            const int mbase = bm + wr * 64 + mi * 16 + 4 * g;
            if constexpr (HEADOUT) {
                const int bb = mbase >> 11, ss = mbase & 2047;
                const int hh = n >> 6, hd = n & 63;
                if (z == 2) {
                    // V blocked: panel = ss>>5, elem = hd*32 + (ss&31)
                    union { ushort4 u; unsigned short s[4]; } pk;
                    #pragma unroll
                    for (int r = 0; r < 4; ++r) pk.s[r] = f32_to_bf16_bits(v[r]);
                    *reinterpret_cast<ushort4*>(
                        Hout + (size_t)2 * HEADMAT +
                        (size_t)(bb * Hc + hh) * Sc * HDc +
                        (size_t)(ss >> 5) * (HDc * 32) + hd * 32 + (ss & 31)) = pk.u;
                } else {
                    #pragma unroll
                    for (int r = 0; r < 4; ++r)
                        Hout[(size_t)z * HEADMAT +
                             (((size_t)(bb * Hc + hh) * Sc + ss + r) * HDc + hd)] =
                            f32_to_bf16_bits(v[r]);
                }
            } else {
                #pragma unroll
                for (int r = 0; r < 4; ++r)
                    Yf[(size_t)(mbase + r) * 512 + n] = v[r];
            }
        }
    }
}

// ---------------------------------------------------------------------------
// Split-K flash attention (R18-verified, 58us): 32x32 swapped-QK MFMA,
// in-lane softmax, blocked V panels, Q pre-scaled, LPT + XCD swizzle,
// 4-wave split-K with LDS-overlay combine.
// ---------------------------------------------------------------------------
__global__ __launch_bounds__(256)
void attn_mfma(const short* __restrict__ Qh, const short* __restrict__ Kh,
               const short* __restrict__ Vb, const int* __restrict__ mask,
               unsigned short* __restrict__ Ob)
{
    // per-wave overlay: Lacc[64][33] f32 (8448B); Lml 256B/wave
    __shared__ __align__(16) char smem[4 * 8448 + 4 * 256];

    const int lane = threadIdx.x & 63;
    const int wave = threadIdx.x >> 6;
    const int bid  = blockIdx.x;                    // 1024 blocks
    const int swz  = (bid & 7) * 128 + (bid >> 3);  // XCD-chunked, bijective
    const int t    = 63 - (swz & 63);               // LPT: big tiles first
    const int h    = (swz >> 6) & 7;
    const int b    = swz >> 9;
    const int q0   = t * 32;
    const int r32  = lane & 31;
    const int hi   = lane >> 5;

    char*  wreg = smem + wave * 8448;
    float* Lml  = (float*)(smem + 4 * 8448 + wave * 256);

    const size_t headoff = (size_t)(b * Hc + h) * Sc * HDc;
    const short* Qp = Qh + headoff;
    const short* Kp = Kh + headoff;
    const short* Vp = Vb + headoff;                 // blocked [S/32][64][32]
    const int* mb = mask + b * Sc;

    // first unmasked key (block-uniform)
    int fb = Sc;
    for (int base = 0; base < Sc; base += 64) {
        unsigned long long bal = __ballot(mb[base + lane] != 0);
        if (bal) { fb = base + (__ffsll(bal) - 1); break; }
    }
    const int kmax = (fb <= q0) ? (q0 + 32) : Sc;
    const int kend = (kmax + 31) & ~31;
    const int nT   = kend >> 5;
    const int tpw  = (nT + 3) >> 2;
    const int kbeg = wave * tpw * 32;
    const int kfin = min(kend, kbeg + tpw * 32);

    // Q fragments (B-operand): Q[q=r32][d = 16j + 8hi + e]  (pre-scaled)
    short8 qf[4];
    #pragma unroll
    for (int j = 0; j < 4; ++j)
        qf[j] = *(const short8*)(Qp + (size_t)(q0 + r32) * HDc + j * 16 + hi * 8);

    f32x16 acc0 = {0,0,0,0,0,0,0,0,0,0,0,0,0,0,0,0};
    f32x16 acc1 = {0,0,0,0,0,0,0,0,0,0,0,0,0,0,0,0};
    float m = -1e30f, l = 0.0f;

    // per-lane V offsets within a panel (elements)
    const int vo0 = r32 * 32 + 8 * hi;
    const int vo1 = (32 + r32) * 32 + 8 * hi;

    for (int k0 = kbeg; k0 < kfin; k0 += 32) {
        // --- V fragments: blocked-panel loads
        const short* vpan = Vp + (size_t)k0 * 64;
        const short8 va0 = *(const short8*)(vpan + vo0);
        const short8 va1 = *(const short8*)(vpan + vo0 + 16);
        const short8 vb0 = *(const short8*)(vpan + vo1);
        const short8 vb1 = *(const short8*)(vpan + vo1 + 16);

        // --- K fragments (A-operand) + QK^T
        f32x16 s = {0,0,0,0,0,0,0,0,0,0,0,0,0,0,0,0};
        #pragma unroll
        for (int j = 0; j < 4; ++j) {
            const short8 kf =
                *(const short8*)(Kp + (size_t)(k0 + r32) * HDc + j * 16 + hi * 8);
            s = MFMA32(kf, qf[j], s, 0, 0, 0);
        }

        // --- padding-mask bits (ballot -> wave-uniform word)
        const unsigned long long bal = __ballot(mb[k0 + r32] != 0);
        const unsigned int mloc = ((unsigned int)bal) >> (4 * hi);

        float e[16];
        float tmax = -1e30f;
        if (k0 + 31 > q0) {   // diagonal tile: causal compares needed
            #pragma unroll
            for (int r = 0; r < 16; ++r) {
                const int cr0 = (r & 3) + 8 * (r >> 2);
                float ev = s[r];
                if (!((mloc >> cr0) & 1))            ev -= NEG2;
                if (k0 + cr0 + 4 * hi > q0 + r32)    ev -= NEG2;
                e[r] = ev;
                tmax = fmaxf(tmax, ev);
            }
        } else {
            #pragma unroll
            for (int r = 0; r < 16; ++r) {
                const int cr0 = (r & 3) + 8 * (r >> 2);
                float ev = s[r];
                if (!((mloc >> cr0) & 1))            ev -= NEG2;
                e[r] = ev;
                tmax = fmaxf(tmax, ev);
            }
        }
        tmax = fmaxf(tmax, __shfl_xor(tmax, 32));   // full-row max

        if (__any(tmax > m)) {
            const float mn   = fmaxf(m, tmax);
            const float corr = __builtin_exp2f(m - mn);
            m = mn; l *= corr;
            acc0 *= corr;
            acc1 *= corr;
        }

        float ps = 0.f;
        #pragma unroll
        for (int r = 0; r < 16; ++r) {
            e[r] = __builtin_exp2f(e[r] - m);   // e[] now holds p
            ps += e[r];
        }
        l += ps;

        // --- pack P pairs (HW cvt_pk) and exchange across lane-halves
        const unsigned int A0 = pk2bf(e[0],  e[1]),  B0 = pk2bf(e[2],  e[3]);
        const unsigned int C0 = pk2bf(e[4],  e[5]),  D0 = pk2bf(e[6],  e[7]);
        const unsigned int A1 = pk2bf(e[8],  e[9]),  B1 = pk2bf(e[10], e[11]);
        const unsigned int C1 = pk2bf(e[12], e[13]), D1 = pk2bf(e[14], e[15]);
        const unsigned int A0s = (unsigned int)__shfl_xor((int)A0, 32);
        const unsigned int B0s = (unsigned int)__shfl_xor((int)B0, 32);
        const unsigned int C0s = (unsigned int)__shfl_xor((int)C0, 32);
        const unsigned int D0s = (unsigned int)__shfl_xor((int)D0, 32);
        const unsigned int A1s = (unsigned int)__shfl_xor((int)A1, 32);
        const unsigned int B1s = (unsigned int)__shfl_xor((int)B1, 32);
        const unsigned int C1s = (unsigned int)__shfl_xor((int)C1, 32);
        const unsigned int D1s = (unsigned int)__shfl_xor((int)D1, 32);

        union { unsigned int u[4]; short8 s8; } P0, P1;
        P0.u[0] = hi ? C0s : A0;  P0.u[1] = hi ? D0s : B0;
        P0.u[2] = hi ? C0  : A0s; P0.u[3] = hi ? D0  : B0s;
        P1.u[0] = hi ? C1s : A1;  P1.u[1] = hi ? D1s : B1;
        P1.u[2] = hi ? C1  : A1s; P1.u[3] = hi ? D1  : B1s;

        // --- PV: O^T += V^T_frag x P_frag
        acc0 = MFMA32(va0, P0.s8, acc0, 0, 0, 0);
        acc0 = MFMA32(va1, P1.s8, acc0, 0, 0, 0);
        acc1 = MFMA32(vb0, P0.s8, acc1, 0, 0, 0);
        acc1 = MFMA32(vb1, P1.s8, acc1, 0, 0, 0);
    }

    l += __shfl_xor(l, 32);   // full-row denominator for this wave

    // dump partials into OWN overlay region
    {
        float* Lacc = (float*)wreg;   // [64][33]
        #pragma unroll
        for (int r = 0; r < 16; ++r) {
            Lacc[lane * 33 + r]      = acc0[r];
            Lacc[lane * 33 + 16 + r] = acc1[r];
        }
        if (lane < 32) { Lml[lane] = m; Lml[32 + lane] = l; }
    }
    __syncthreads();

    // combine: per-lane weights (q = r32); wave w handles regs [8w, 8w+8)
    float mu[4], lu[4], M = -1e30f;
    #pragma unroll
    for (int u = 0; u < 4; ++u) {
        const float* LmlU = (const float*)(smem + 4 * 8448 + u * 256);
        mu[u] = LmlU[r32];
        lu[u] = LmlU[32 + r32];
        M = fmaxf(M, mu[u]);
    }
    float wgt[4], L = 0.f;
    #pragma unroll
    for (int u = 0; u < 4; ++u) {
        wgt[u] = __builtin_exp2f(mu[u] - M);
        L += wgt[u] * lu[u];
    }
    const float invL = 1.0f / L;

    #pragma unroll
    for (int jj = 0; jj < 8; ++jj) {
        const int j = wave * 8 + jj;
        float o = 0.f;
        #pragma unroll
        for (int u = 0; u < 4; ++u)
            o += wgt[u] * ((const float*)(smem + u * 8448))[lane * 33 + j];
        const int j16 = j & 15;
        const int d = (j16 & 3) + 8 * (j16 >> 2) + 4 * hi + 32 * (j >> 4);
        Ob[(size_t)(b * Sc + q0 + r32) * Dc + h * HDc + d] =
            f32_to_bf16_bits(o * invL);
    }
}

// ---------------------------------------------------------------------------
extern "C" void kernel_launch(void* const* d_in, const int* in_sizes, int n_in,
                              void* d_out, int out_size, void* d_ws, size_t ws_size,
                              hipStream_t stream) {
    const float* x  = (const float*)d_in[0];
    const int* mask = (const int*)d_in[1];
    const float* Wq = (const float*)d_in[2];
    const float* bq = (const float*)d_in[3];
    const float* Wk = (const float*)d_in[4];
    const float* bk = (const float*)d_in[5];
    const float* Wv = (const float*)d_in[6];
    const float* bv = (const float*)d_in[7];
    const float* Wo = (const float*)d_in[8];
    const float* bo = (const float*)d_in[9];
    float* out = (float*)d_out;   // reference output dtype is float32

    unsigned short* Wt = (unsigned short*)d_ws;          // 2 MB
    unsigned short* Qh = Wt + (size_t)4 * 512 * 512;     // head-major (xSC2)
    unsigned short* Kh = Qh + HEADMAT;                   // head-major
    unsigned short* Vb = Kh + HEADMAT;                   // BLOCKED panels
    unsigned short* Ob = Vb + HEADMAT;

    transpose_w<<<dim3(8, 8, 4), dim3(256), 0, stream>>>(Wq, Wk, Wv, Wo, Wt);
    // QKV projections: x read as f32, converted during staging (no convert_x)
    gemm_tile<true><<<dim3(8, Mtot / 128, 3), dim3(256), 0, stream>>>(
        x, Wt, bq, bk, bv, Qh, nullptr);
    attn_mfma<<<dim3(1024), dim3(256), 0, stream>>>(
        (const short*)Qh, (const short*)Kh, (const short*)Vb, mask, Ob);
    gemm_tile<false><<<dim3(8, Mtot / 128, 1), dim3(256), 0, stream>>>(
        Ob, Wt + (size_t)3 * 512 * 512, bo, bo, bo, nullptr, out);
}